// Round 1
// 123.856 us; speedup vs baseline: 1.0816x; 1.0816x over previous
//
#include <hip/hip_runtime.h>

#define TSTEPS 1024
#define NROWS  8192
#define CLEN   16      // steps per chunk = steps per lane
#define KEPS   1e-6f

__device__ __forceinline__ float clampP(float x) {
    return fminf(fmaxf(x, KEPS), 1.f - KEPS);
}
__device__ __forceinline__ float sigm(float v) {
    return 1.0f / (1.0f + __expf(-v));
}

// ---------------- K1: per-row MLP -> params {l,g,s,prior}; 4 rows/wave, 16 rows/block ----
__global__ __launch_bounds__(256) void bkt_params_v4(
    const int* __restrict__ X, const float* __restrict__ embed,
    const float* __restrict__ W0, const float* __restrict__ b0,
    const float* __restrict__ W1, const float* __restrict__ b1,
    const float* __restrict__ Wout, const float* __restrict__ bout,
    float4* __restrict__ params)
{
    const int lane    = threadIdx.x & 63;
    const int wid     = threadIdx.x >> 6;
    const int rowbase = blockIdx.x * 16 + wid * 4;

    __shared__ float sh[4][4][64];
    float (*shw)[64] = sh[wid];

    #pragma unroll
    for (int rs = 0; rs < 4; ++rs) {
        const int skill = X[rowbase + rs];
        shw[rs][lane] = embed[(size_t)skill * 64 + lane];
    }
    __syncthreads();

    float a0 = b0[lane], a1 = a0, a2 = a0, a3 = a0;
    #pragma unroll
    for (int k4 = 0; k4 < 16; ++k4) {
        const float4 e0 = *(const float4*)&shw[0][k4 * 4];
        const float4 e1 = *(const float4*)&shw[1][k4 * 4];
        const float4 e2 = *(const float4*)&shw[2][k4 * 4];
        const float4 e3 = *(const float4*)&shw[3][k4 * 4];
        const float w0 = W0[(k4 * 4 + 0) * 64 + lane];
        const float w1 = W0[(k4 * 4 + 1) * 64 + lane];
        const float w2 = W0[(k4 * 4 + 2) * 64 + lane];
        const float w3 = W0[(k4 * 4 + 3) * 64 + lane];
        a0 = fmaf(e0.x, w0, a0); a0 = fmaf(e0.y, w1, a0); a0 = fmaf(e0.z, w2, a0); a0 = fmaf(e0.w, w3, a0);
        a1 = fmaf(e1.x, w0, a1); a1 = fmaf(e1.y, w1, a1); a1 = fmaf(e1.z, w2, a1); a1 = fmaf(e1.w, w3, a1);
        a2 = fmaf(e2.x, w0, a2); a2 = fmaf(e2.y, w1, a2); a2 = fmaf(e2.z, w2, a2); a2 = fmaf(e2.w, w3, a2);
        a3 = fmaf(e3.x, w0, a3); a3 = fmaf(e3.y, w1, a3); a3 = fmaf(e3.z, w2, a3); a3 = fmaf(e3.w, w3, a3);
    }
    __syncthreads();
    shw[0][lane] = fmaxf(a0, 0.f);
    shw[1][lane] = fmaxf(a1, 0.f);
    shw[2][lane] = fmaxf(a2, 0.f);
    shw[3][lane] = fmaxf(a3, 0.f);
    __syncthreads();

    a0 = b1[lane]; a1 = a0; a2 = a0; a3 = a0;
    #pragma unroll
    for (int k4 = 0; k4 < 16; ++k4) {
        const float4 e0 = *(const float4*)&shw[0][k4 * 4];
        const float4 e1 = *(const float4*)&shw[1][k4 * 4];
        const float4 e2 = *(const float4*)&shw[2][k4 * 4];
        const float4 e3 = *(const float4*)&shw[3][k4 * 4];
        const float w0 = W1[(k4 * 4 + 0) * 64 + lane];
        const float w1 = W1[(k4 * 4 + 1) * 64 + lane];
        const float w2 = W1[(k4 * 4 + 2) * 64 + lane];
        const float w3 = W1[(k4 * 4 + 3) * 64 + lane];
        a0 = fmaf(e0.x, w0, a0); a0 = fmaf(e0.y, w1, a0); a0 = fmaf(e0.z, w2, a0); a0 = fmaf(e0.w, w3, a0);
        a1 = fmaf(e1.x, w0, a1); a1 = fmaf(e1.y, w1, a1); a1 = fmaf(e1.z, w2, a1); a1 = fmaf(e1.w, w3, a1);
        a2 = fmaf(e2.x, w0, a2); a2 = fmaf(e2.y, w1, a2); a2 = fmaf(e2.z, w2, a2); a2 = fmaf(e2.w, w3, a2);
        a3 = fmaf(e3.x, w0, a3); a3 = fmaf(e3.y, w1, a3); a3 = fmaf(e3.z, w2, a3); a3 = fmaf(e3.w, w3, a3);
    }
    const float h0r = fmaxf(a0, 0.f), h1r = fmaxf(a1, 0.f);
    const float h2r = fmaxf(a2, 0.f), h3r = fmaxf(a3, 0.f);

    const float4 wo = ((const float4*)Wout)[lane];
    float p[4][4];
    p[0][0] = h0r * wo.x; p[0][1] = h0r * wo.y; p[0][2] = h0r * wo.z; p[0][3] = h0r * wo.w;
    p[1][0] = h1r * wo.x; p[1][1] = h1r * wo.y; p[1][2] = h1r * wo.z; p[1][3] = h1r * wo.w;
    p[2][0] = h2r * wo.x; p[2][1] = h2r * wo.y; p[2][2] = h2r * wo.z; p[2][3] = h2r * wo.w;
    p[3][0] = h3r * wo.x; p[3][1] = h3r * wo.y; p[3][2] = h3r * wo.z; p[3][3] = h3r * wo.w;
    #pragma unroll
    for (int off = 32; off >= 1; off >>= 1) {
        #pragma unroll
        for (int rs = 0; rs < 4; ++rs)
            #pragma unroll
            for (int c = 0; c < 4; ++c)
                p[rs][c] += __shfl_xor(p[rs][c], off, 64);
    }
    const float4 bo = *(const float4*)bout;
    float v0 = (lane == 0) ? p[0][0] : (lane == 1) ? p[1][0] : (lane == 2) ? p[2][0] : p[3][0];
    float v1 = (lane == 0) ? p[0][1] : (lane == 1) ? p[1][1] : (lane == 2) ? p[2][1] : p[3][1];
    float v2 = (lane == 0) ? p[0][2] : (lane == 1) ? p[1][2] : (lane == 2) ? p[2][2] : p[3][2];
    float v3 = (lane == 0) ? p[0][3] : (lane == 1) ? p[1][3] : (lane == 2) ? p[2][3] : p[3][3];
    if (lane < 4) {
        float4 r;
        r.x = clampP(sigm(v0 + bo.x));
        r.y = clampP(sigm(v1 + bo.y));
        r.z = clampP(sigm(v2 + bo.z));
        r.w = clampP(sigm(v3 + bo.w));
        params[rowbase + lane] = r;
    }
}

// ---------------- K2: one wave per row; lane = 16-step time chunk ----------------
// v5: coalesced y loads (ballot bit-redistribution) + LDS-transposed coalesced stores.
__global__ __launch_bounds__(256) void bkt_scan_v5(
    const int* __restrict__ y, const float4* __restrict__ params,
    float* __restrict__ out_corr, float* __restrict__ out_lat)
{
    const int lane = threadIdx.x & 63;
    const int wid  = threadIdx.x >> 6;
    const int row  = blockIdx.x * 4 + wid;

    // Per-wave transpose buffers: stride 17 floats -> 2-way bank aliasing (free).
    __shared__ float shbuf[4][2][64 * 17];   // 34816 B
    float* shc = shbuf[wid][0];
    float* shl = shbuf[wid][1];

    const float4 p = params[row];
    const float l = p.x, g = p.y, s = p.z, prior = p.w;

    // ---- Phase A: coalesced y loads (4 x 1KB contiguous per wave) ----
    // load j, lane i holds y[t] for t = j*256 + 4i + e (e=0..3)
    const int4* yrow = (const int4*)(y + (size_t)row * TSTEPS);
    unsigned long long B[4][4];
    #pragma unroll
    for (int j = 0; j < 4; ++j) {
        const int4 v = yrow[j * 64 + lane];
        B[j][0] = __ballot(v.x > 0);
        B[j][1] = __ballot(v.y > 0);
        B[j][2] = __ballot(v.z > 0);
        B[j][3] = __ballot(v.w > 0);
    }
    // chunk c = lane owns t = 16c+q. bit q lives at ballot[j=c>>4][e=q&3],
    // bit index 4*(c&15) + (q>>2). Gather 4-bit nibble per e, spread k->4k.
    const int jsel  = lane >> 4;
    const int ibase = (lane & 15) * 4;
    unsigned msk = 0;
    #pragma unroll
    for (int e = 0; e < 4; ++e) {
        const unsigned long long be =
            (jsel == 0) ? B[0][e] : (jsel == 1) ? B[1][e] :
            (jsel == 2) ? B[2][e] : B[3][e];
        const unsigned n  = (unsigned)(be >> ibase) & 0xFu;
        const unsigned sp = (n & 1u) | ((n & 2u) << 3) | ((n & 4u) << 6) | ((n & 8u) << 9);
        msk |= sp << e;
    }

    // step as Mobius: L' = (m00*L+m01)/(m10*L+m11)
    const float c1 = 1.f - s - g, d1 = g;             // y=1 denominator coeffs
    const float e00_1 = fmaf(l, c1, (1.f - l) * (1.f - s));
    const float e01_1 = l * d1;
    const float c0 = s + g - 1.f, d0 = 1.f - g;       // y=0
    const float e00_0 = fmaf(l, c0, (1.f - l) * s);
    const float e01_0 = l * d0;

    // Phase C: compose my chunk's 16 step matrices (renorm every 4; m11 > 0)
    float m00 = 1.f, m01 = 0.f, m10 = 0.f, m11 = 1.f;
    #pragma unroll
    for (int t = 0; t < CLEN; ++t) {
        const bool one = (msk >> t) & 1u;
        const float e00 = one ? e00_1 : e00_0;
        const float e01 = one ? e01_1 : e01_0;
        const float e10 = one ? c1 : c0;
        const float e11 = one ? d1 : d0;
        const float n00 = fmaf(e00, m00, e01 * m10);
        const float n01 = fmaf(e00, m01, e01 * m11);
        const float n10 = fmaf(e10, m00, e11 * m10);
        const float n11 = fmaf(e10, m01, e11 * m11);
        if ((t & 3) == 3) {
            const float inv = __builtin_amdgcn_rcpf(n11);
            m00 = n00 * inv; m01 = n01 * inv; m10 = n10 * inv; m11 = 1.f;
        } else {
            m00 = n00; m01 = n01; m10 = n10; m11 = n11;
        }
    }

    // Phase D: inclusive Hillis-Steele prefix over the 64 chunk matrices
    float s00 = m00, s01 = m01, s10 = m10, s11 = m11;
    #pragma unroll
    for (int d = 1; d < 64; d <<= 1) {
        const float t00 = __shfl_up(s00, d, 64);
        const float t01 = __shfl_up(s01, d, 64);
        const float t10 = __shfl_up(s10, d, 64);
        const float t11 = __shfl_up(s11, d, 64);
        if (lane >= d) {
            const float r00 = fmaf(s00, t00, s01 * t10);
            const float r01 = fmaf(s00, t01, s01 * t11);
            const float r10 = fmaf(s10, t00, s11 * t10);
            const float r11 = fmaf(s10, t01, s11 * t11);
            const float inv = __builtin_amdgcn_rcpf(r11);
            s00 = r00 * inv; s01 = r01 * inv; s10 = r10 * inv; s11 = 1.f;
        }
    }
    // exclusive prefix -> my chunk-start latent
    const float x00 = __shfl_up(s00, 1, 64);
    const float x01 = __shfl_up(s01, 1, 64);
    const float x10 = __shfl_up(s10, 1, 64);
    const float x11 = __shfl_up(s11, 1, 64);
    float L0;
    if (lane == 0) {
        L0 = prior;
    } else {
        const float num = fmaf(x00, prior, x01);
        const float den = fmaf(x10, prior, x11);
        L0 = clampP(num * __builtin_amdgcn_rcpf(den));
    }

    // Phase E: exact clipped recurrence for my 16 steps, all into registers
    const float a   = 1.f - s;
    const float omg = 1.f - g;
    const float oml = 1.f - l;
    float cr[CLEN], lt[CLEN];
    float Lc = L0;
    #pragma unroll
    for (int t = 0; t < CLEN; ++t) {
        const float correct = fmaf(Lc, c1, g);    // L*(1-s-g)+g
        const float den0    = fmaf(Lc, c0, omg);  // L*(s+g-1)+(1-g)
        const float k1 = (Lc * a) * __builtin_amdgcn_rcpf(correct);
        const float k0 = (Lc * s) * __builtin_amdgcn_rcpf(den0);
        const bool one = (msk >> t) & 1u;
        const float k = one ? k1 : k0;
        cr[t] = correct;
        lt[t] = Lc;
        Lc = clampP(fmaf(k, oml, l));
    }

    // Phase F: LDS transpose (chunk-major -> time-major) + coalesced 1KB stores
    #pragma unroll
    for (int t = 0; t < CLEN; ++t) {
        shc[lane * 17 + t] = cr[t];
        shl[lane * 17 + t] = lt[t];
    }
    __syncthreads();

    float* oc = out_corr + (size_t)row * TSTEPS;
    float* ol = out_lat  + (size_t)row * TSTEPS;
    #pragma unroll
    for (int j = 0; j < 4; ++j) {
        // store word j: lane i writes t = j*256 + 4i .. +3 (contiguous across wave)
        const int c    = j * 16 + (lane >> 2);
        const int q    = (lane & 3) * 4;
        const int base = c * 17 + q;
        float4 vc, vl;
        vc.x = shc[base + 0]; vc.y = shc[base + 1]; vc.z = shc[base + 2]; vc.w = shc[base + 3];
        vl.x = shl[base + 0]; vl.y = shl[base + 1]; vl.z = shl[base + 2]; vl.w = shl[base + 3];
        *(float4*)(oc + j * 256 + lane * 4) = vc;
        *(float4*)(ol + j * 256 + lane * 4) = vl;
    }
}

extern "C" void kernel_launch(void* const* d_in, const int* in_sizes, int n_in,
                              void* d_out, int out_size, void* d_ws, size_t ws_size,
                              hipStream_t stream) {
    const int*   X     = (const int*)  d_in[0];
    const int*   y     = (const int*)  d_in[1];
    const float* embed = (const float*)d_in[2];
    const float* W0    = (const float*)d_in[3];
    const float* b0    = (const float*)d_in[4];
    const float* W1    = (const float*)d_in[5];
    const float* b1    = (const float*)d_in[6];
    const float* Wout  = (const float*)d_in[7];
    const float* bout  = (const float*)d_in[8];

    float* out_corr = (float*)d_out;
    float* out_lat  = out_corr + (size_t)NROWS * TSTEPS;
    float4* paramsb = (float4*)d_ws;   // 128 KB scratch

    bkt_params_v4<<<NROWS / 16, 256, 0, stream>>>(X, embed, W0, b0, W1, b1, Wout, bout, paramsb);
    bkt_scan_v5 <<<NROWS / 4,  256, 0, stream>>>(y, paramsb, out_corr, out_lat);
}